// Round 4
// baseline (320.760 us; speedup 1.0000x reference)
//
#include <hip/hip_runtime.h>
#include <stdint.h>

// ============================================================================
// CPM layer, bit-exact JAX reproduction. B=8, C=8, H=W=1024.
// Round 4: ch1-7 pass-through copy is fused INTO the 8 half_step launches
// (16:7 compute:copy block interleave) to hide the 470 MB copy under the
// VALU-bound Metropolis compute. prep goes back to compute-only.
// RNG / dot-product / exp unchanged from the PASSING round-3 kernel.
// ============================================================================

#define HW   1048576    // 1024*1024
#define BHWu 8388608u   // 8*HW
#define NHu  4194304u   // BHW/2 = active pixels per parity

// copy geometry: ch1-7 float4 count = 8b * 7c * 262144 = 14,680,064
//   per step slice: 1,835,008 float4 = 7168 blocks * 256 threads
#define COPY_BLOCKS_PER_STEP 7168
#define COMPUTE_BLOCKS       16384

// ---------------------------------------------------------------------- RNG
__device__ __host__ __forceinline__ void tf2x32(uint32_t k0, uint32_t k1,
                                                uint32_t x0, uint32_t x1,
                                                uint32_t& o0, uint32_t& o1) {
  uint32_t k2 = k0 ^ k1 ^ 0x1BD11BDAu;
  x0 += k0; x1 += k1;
#define RDD(r) { x0 += x1; x1 = (x1 << (r)) | (x1 >> (32 - (r))); x1 ^= x0; }
  RDD(13) RDD(15) RDD(26) RDD(6)
  x0 += k1; x1 += k2 + 1u;
  RDD(17) RDD(29) RDD(16) RDD(24)
  x0 += k2; x1 += k0 + 2u;
  RDD(13) RDD(15) RDD(26) RDD(6)
  x0 += k0; x1 += k1 + 3u;
  RDD(17) RDD(29) RDD(16) RDD(24)
  x0 += k1; x1 += k2 + 4u;
  RDD(13) RDD(15) RDD(26) RDD(6)
  x0 += k2; x1 += k0 + 5u;
#undef RDD
  o0 = x0; o1 = x1;
}

// ------------------------------------------------- XLA-CPU Cephes expf clone
__device__ __forceinline__ float xla_expf(float input) {
  float x  = fmaxf(fminf(input, 88.3762626647950f), -88.3762626647949f);
  float fx = floorf(fmaf(x, 1.44269504088896341f, 0.5f));
  float tmp = __fmul_rn(0.693359375f, fx);
  float z   = __fmul_rn(-2.12194440e-4f, fx);
  x = __fsub_rn(x, tmp);
  x = __fsub_rn(x, z);
  z = __fmul_rn(x, x);
  float y = fmaf(x, 1.9875691500e-4f, 1.3981999507e-3f);
  y = fmaf(y, x, 8.3334519073e-3f);
  y = fmaf(y, x, 4.1665795894e-2f);
  y = fmaf(y, x, 1.6666665459e-1f);
  y = fmaf(y, x, 5.0000001201e-1f);
  y = fmaf(y, z, x);
  y = __fadd_rn(y, 1.0f);
  int n = (int)fx;
  float p2n = __int_as_float((n + 127) << 23);
  return fmaxf(__fmul_rn(y, p2n), input);
}

// ------------------------------------------------------------------- kernels
// prep4: 4 px/thread, compute-only (read X 8ch, write parity-packed dHNN + ids).
__global__ __launch_bounds__(256) void prep4(const float* __restrict__ X,
                                             const float* __restrict__ W,
                                             const float* __restrict__ Bb,
                                             float* __restrict__ dHNN,
                                             uint8_t* __restrict__ ids) {
  int tid = blockIdx.x * 256 + threadIdx.x;   // 0 .. BHW/4-1
  int e   = tid << 2;                          // pixel base (x0 multiple of 4)
  int b   = e >> 20;
  int yx  = e & (HW - 1);
  int y   = yx >> 10;
  int x0  = yx & 1023;
  int q4  = yx >> 2;                           // float4 index within plane
  const float4* xb = (const float4*)(X + ((size_t)b << 23));
  float4 xc[8];
#pragma unroll
  for (int c = 0; c < 8; c++) xc[c] = xb[(c << 18) + q4];
#pragma unroll
  for (int j = 0; j < 4; j++) {
    float4 r;
#pragma unroll
    for (int o = 0; o < 4; o++) {
      float acc = 0.0f;
#pragma unroll
      for (int c = 0; c < 8; c++)
        acc = __fadd_rn(acc, __fmul_rn(((const float*)&xc[c])[j], W[o * 8 + c]));
      ((float*)&r)[o] = __fadd_rn(acc, Bb[o]);
    }
    int xj  = x0 + j;
    int sub = (y + xj) & 1;
    int q   = (b << 19) | (y << 9) | (xj >> 1);
    ((float4*)dHNN)[sub * NHu + (uint32_t)q] = r;
  }
  uchar4 v;
  v.x = (uint8_t)(int)((const float*)&xc[0])[0];
  v.y = (uint8_t)(int)((const float*)&xc[0])[1];
  v.z = (uint8_t)(int)((const float*)&xc[0])[2];
  v.w = (uint8_t)(int)((const float*)&xc[0])[3];
  *(uchar4*)(ids + e) = v;
}

// half_step: compute blocks do the Metropolis update (bit-exact, in-place,
// race-free by checkerboard parity). With FUSE=1, interleaved copy blocks
// stream 1/8 of the X ch1-7 pass-through into out (independent data).
// Grid (FUSE=1): 1024 groups of 23 blocks = 16 compute + 7 copy.
template <int FUSE>
__global__ __launch_bounds__(256) void half_step(uint8_t* __restrict__ ids,
                                                 const float* __restrict__ dHNN,
                                                 const float* __restrict__ X,
                                                 float* __restrict__ out,
                                                 uint32_t dk0, uint32_t dk1,
                                                 uint32_t uk0, uint32_t uk1,
                                                 int sub, int step) {
  int cb;  // compute block index
  if (FUSE) {
    int g = blockIdx.x;
    int group = g / 23, r0 = g - group * 23;
    if (r0 >= 16) {
      // ---- copy role: 256 float4 of the ch1-7 pass-through
      int pi = group * 7 + (r0 - 16);
      int f  = (step * COPY_BLOCKS_PER_STEP + pi) * 256 + (int)threadIdx.x;
      int bc = f >> 18;                   // 262144 float4 per plane
      int q4 = f & 262143;
      int b  = bc / 7;
      int c  = bc - b * 7 + 1;            // channel 1..7
      size_t off = ((size_t)b << 23) + ((size_t)c << 20);
      ((float4*)(out + off))[q4] = ((const float4*)(X + off))[q4];
      return;
    }
    cb = group * 16 + r0;
  } else {
    cb = blockIdx.x;
  }

  int t = cb * 256 + (int)threadIdx.x;        // 0 .. NH-1 (== packed index)
  int b = t >> 19;
  int r = t & 524287;
  int y = r >> 9;
  int i = r & 511;
  int x = (i << 1) | ((y + sub) & 1);         // (y+x)%2 == sub
  int p = (b << 20) | (y << 10) | x;

  float4 dnn = ((const float4*)dHNN)[sub * NHu + (uint32_t)t];

  uint32_t d0, d1, u0, u1;
  tf2x32(dk0, dk1, 0u, (uint32_t)p, d0, d1);  // randint lower_bits
  uint32_t db = d0 ^ d1;
  tf2x32(uk0, uk1, 0u, (uint32_t)p, u0, u1);  // uniform bits
  uint32_t ub = u0 ^ u1;
  int   dir = (int)(db & 3u);
  float u   = __fsub_rn(__uint_as_float((ub >> 9) | 0x3F800000u), 1.0f);

  int yN = (y + 1) & 1023, yP = (y - 1) & 1023;
  int xN = (x + 1) & 1023, xP = (x - 1) & 1023;
  int base = b << 20;
  uint32_t c  = ids[p];
  uint32_t n0 = ids[base + (yN << 10) + x];   // roll(-1,0): ids[y+1]
  uint32_t n1 = ids[base + (yP << 10) + x];   // roll(+1,0): ids[y-1]
  uint32_t n2 = ids[base + (y << 10) + xN];   // roll(0,-1): ids[x+1]
  uint32_t n3 = ids[base + (y << 10) + xP];   // roll(0,+1): ids[x-1]
  uint32_t s  = (dir == 0) ? n0 : (dir == 1) ? n1 : (dir == 2) ? n2 : n3;
  float dH_nn = (dir == 0) ? dnn.x : (dir == 1) ? dnn.y : (dir == 2) ? dnn.z : dnn.w;
  int dadh = ((int)(n0 != s) + (n1 != s) + (n2 != s) + (n3 != s))
           - ((int)(n0 != c) + (n1 != c) + (n2 != c) + (n3 != c));
  float dH = __fadd_rn((float)dadh, dH_nn);
  if (u < xla_expf(-dH)) ids[p] = (uint8_t)s;
}

// finalize_ch0: out channel 0 <- ids (4 px/thread).
__global__ __launch_bounds__(256) void finalize_ch0(const uint8_t* __restrict__ ids,
                                                    float* __restrict__ out) {
  int tid = blockIdx.x * 256 + threadIdx.x;   // 0 .. BHW/4-1
  int e   = tid << 2;
  int b   = e >> 20;
  int yx  = e & (HW - 1);
  uchar4 v = *(const uchar4*)(ids + e);
  float4 r;
  r.x = (float)v.x; r.y = (float)v.y; r.z = (float)v.z; r.w = (float)v.w;
  ((float4*)(out + ((size_t)b << 23)))[yx >> 2] = r;
}

// finalize_full: fallback (dHNN lived in out) — rewrite all of out from X+ids.
__global__ __launch_bounds__(256) void finalize_full(const float* __restrict__ X,
                                                     const uint8_t* __restrict__ ids,
                                                     float* __restrict__ out) {
  int t = blockIdx.x * 256 + threadIdx.x;
  int e = t << 2;
  int c = (e >> 20) & 7;
  float4 r;
  if (c == 0) {
    int b  = e >> 23;
    int yx = e & (HW - 1);
    uchar4 v = *(const uchar4*)(ids + ((size_t)b << 20) + yx);
    r.x = (float)v.x; r.y = (float)v.y; r.z = (float)v.z; r.w = (float)v.w;
  } else {
    r = ((const float4*)X)[t];
  }
  ((float4*)out)[t] = r;
}

// --------------------------------------------------------------------- host
extern "C" void kernel_launch(void* const* d_in, const int* in_sizes, int n_in,
                              void* d_out, int out_size, void* d_ws, size_t ws_size,
                              hipStream_t stream) {
  const float* X  = (const float*)d_in[0];
  const float* W  = (const float*)d_in[1];
  const float* Bb = (const float*)d_in[2];
  float* out = (float*)d_out;

  const size_t DHNN_BYTES = (size_t)BHWu * 16u;       // 134 MB
  const size_t IDS_BYTES  = (size_t)BHWu;             // 8.4 MB
  bool ws_ok = ws_size >= DHNN_BYTES + IDS_BYTES;

  float*   dHNN = ws_ok ? (float*)d_ws : out;
  uint8_t* ids  = ws_ok ? (uint8_t*)d_ws + DHNN_BYTES : (uint8_t*)d_ws;

  prep4<<<8192, 256, 0, stream>>>(X, W, Bb, dHNN, ids);

  // Host-side threefry key chain (partitionable stream; verified round 2).
  uint32_t bk0 = 0u, bk1 = 42u;                        // jax.random.key(42)
  uint32_t keys[8][2];
  for (uint32_t t = 0; t < 8; t++)
    tf2x32(bk0, bk1, 0u, t, keys[t][0], keys[t][1]);   // fold-like split
  for (int t = 0; t < 8; t++) {
    uint32_t dk0, dk1, uk0, uk1, k1a, k1b;
    tf2x32(keys[t][0], keys[t][1], 0u, 0u, k1a, k1b);  // k1 (randint arg key)
    tf2x32(keys[t][0], keys[t][1], 0u, 1u, uk0, uk1);  // k2 (uniform key)
    tf2x32(k1a, k1b, 0u, 1u, dk0, dk1);                // randint internal kk2
    if (ws_ok)
      half_step<1><<<COMPUTE_BLOCKS + COPY_BLOCKS_PER_STEP, 256, 0, stream>>>(
          ids, dHNN, X, out, dk0, dk1, uk0, uk1, t & 1, t);
    else
      half_step<0><<<COMPUTE_BLOCKS, 256, 0, stream>>>(
          ids, dHNN, X, out, dk0, dk1, uk0, uk1, t & 1, t);
  }

  if (ws_ok) finalize_ch0<<<8192, 256, 0, stream>>>(ids, out);
  else       finalize_full<<<65536, 256, 0, stream>>>(X, ids, out);
  (void)in_sizes; (void)n_in; (void)out_size;
}